// Round 5
// baseline (132.263 us; speedup 1.0000x reference)
//
#include <hip/hip_runtime.h>
#include <math.h>

// Problem constants
#define BB    16
#define TT    2048
#define VOCAB 14
#define TOKD  8
#define POSD  8
#define DM    16      // TOKD + POSD
#define NH    2
#define HD    3
#define AD    6       // NH*HD
#define FFND  3

#define NTOK  (BB*TT)            // 32768
#define BH    (BB*NH)            // 32
// 512-query super-rows s'=0..3; key chunks c=0..2s'+1 → 2+4+6+8 = 20 tiles/bh
#define TPB2  20
#define NTILE2 (BH*TPB2)         // 640 tiles

struct P {
    const int*   idx;
    const float* tok_emb;
    const float* pos_enc;
    const float* Wq;
    const float* Wk;
    const float* Wv;
    const float* Wo;
    const float* ln1w;
    const float* ln1b;
    const float* ln2w;
    const float* ln2b;
    const float* lnfw;
    const float* lnfb;
    const float* W1;
    const float* b1;
    const float* W2;
    const float* b2;
    const float* Wh;
    float*       out;
    float4*      qbuf;   // [BH][TT] prescaled q
    float4*      kvf;    // [BH][TT][2] f32 records: even={k0,k1,k2,0} odd={v0,v1,v2,0}
    float4*      pbuf;   // [BH][8][TT] chunk partials {a0,a1,a2,l}, transposed
};

// ---------------------------------------------------------------------------
// Kernel 1: per-token prep (ONCE per token — no tile redundancy). Proven.
// ---------------------------------------------------------------------------
__global__ __launch_bounds__(256) void prep_kernel(P p) {
    int gid = blockIdx.x * 256 + threadIdx.x;
    if (gid >= NTOK) return;
    int t = gid & (TT - 1);
    int b = gid >> 11;

    float x[DM];
    int tok = p.idx[gid];
    #pragma unroll
    for (int j = 0; j < TOKD; ++j) x[j]        = p.tok_emb[tok * TOKD + j];
    #pragma unroll
    for (int j = 0; j < POSD; ++j) x[TOKD + j] = p.pos_enc[t * POSD + j];

    float m = 0.f;
    #pragma unroll
    for (int j = 0; j < DM; ++j) m += x[j];
    m *= (1.f / DM);
    float v = 0.f;
    #pragma unroll
    for (int j = 0; j < DM; ++j) { float d = x[j] - m; v += d * d; }
    v *= (1.f / DM);
    float rs = rsqrtf(v + 1e-5f);
    float h[DM];
    #pragma unroll
    for (int j = 0; j < DM; ++j)
        h[j] = (x[j] - m) * rs * p.ln1w[j] + p.ln1b[j];

    float q[AD], k[AD], vv[AD];
    #pragma unroll
    for (int a = 0; a < AD; ++a) {
        float sq = 0.f, sk = 0.f, sv = 0.f;
        #pragma unroll
        for (int j = 0; j < 8; ++j) {
            sq = fmaf(p.Wq[a * 8 + j], h[TOKD + j], sq);
            sk = fmaf(p.Wk[a * 8 + j], h[TOKD + j], sk);
            sv = fmaf(p.Wv[a * 8 + j], h[j], sv);
        }
        q[a] = sq; k[a] = sk; vv[a] = sv;
    }

    const float QS = 1.4426950408889634f / 1.7320508075688772f; // log2e/sqrt(HD)
    #pragma unroll
    for (int hh = 0; hh < NH; ++hh) {
        size_t base = (size_t)(b * NH + hh) * TT + t;
        p.qbuf[base] = make_float4(q[hh*3] * QS, q[hh*3+1] * QS, q[hh*3+2] * QS, 0.f);
        p.kvf[base * 2]     = make_float4(k[hh*3],  k[hh*3+1],  k[hh*3+2],  0.f);
        p.kvf[base * 2 + 1] = make_float4(vv[hh*3], vv[hh*3+1], vv[hh*3+2], 0.f);
    }
}

// ---------------------------------------------------------------------------
// Kernel 2: attention tiles, 512-query super-rows. Tile = (bh, 512-row s',
// 256-key chunk c), c <= 2s'+1. Wave wv owns keys [c*256+64wv, +64); lane
// owns queries 512s' + 64j + lane, j=0..7. ONE broadcast ds_read_b128 pair
// per key serves 512 query*key pairs (2x the previous amortization — halves
// per-CU LDS-pipe demand). Diagonal tiles (c>=2s') use a per-pair
// keyloc<=qloc compare mask; odd-diagonal restricts to groups 4..7.
// Q comes straight from global (coalesced) — no LDS staging for q.
// ---------------------------------------------------------------------------
__global__ __launch_bounds__(256) void attn_kernel(P p) {
    __shared__ float4 skv[512];      // 8 KB   K/V records of the 256-key chunk
    __shared__ float4 spart[2048];   // 32 KB  4 waves x 512 query partials

    const int tid  = threadIdx.x;
    int tile = blockIdx.x;
    int bh   = tile / TPB2;
    int r    = tile - bh * TPB2;
    int s    = 0;                              // super-row, prefix s(s+1)
    while ((s + 1) * (s + 2) <= r) ++s;
    int c    = r - s * (s + 1);
    int dpar = c - 2 * s;                      // <0 full, 0 even-diag, 1 odd-diag

    const float4* kvsrc = p.kvf + ((size_t)bh * TT + (c << 8)) * 2;
    skv[tid]       = kvsrc[tid];
    skv[256 + tid] = kvsrc[256 + tid];

    int wv   = tid >> 6;
    int lane = tid & 63;
    int kb   = wv << 6;                        // local key base within chunk

    // Q direct from global, coalesced: query = 512s' + 64j + lane
    float qx[8], qy[8], qz[8];
    const float4* qsrc = p.qbuf + (size_t)bh * TT + ((size_t)s << 9);
    #pragma unroll
    for (int j = 0; j < 8; ++j) {
        float4 q4 = qsrc[(j << 6) + lane];
        qx[j] = q4.x; qy[j] = q4.y; qz[j] = q4.z;
    }

    float ac[8][4];
    #pragma unroll
    for (int j = 0; j < 8; ++j)
        ac[j][0] = ac[j][1] = ac[j][2] = ac[j][3] = 0.f;

    __syncthreads();                           // skv ready

    // One ds_read_b128 pair per key in ALL paths.
    #define KLOOP(J0, MASKED, KOFF)                                           \
        _Pragma("unroll 2")                                                   \
        for (int it = 0; it < 64; ++it) {                                     \
            float4 Kr = skv[(kb + it) << 1];                                  \
            float4 Vr = skv[((kb + it) << 1) + 1];                            \
            float k0 = Kr.x, k1 = Kr.y, k2 = Kr.z;                            \
            float v0 = Vr.x, v1 = Vr.y, v2 = Vr.z;                            \
            int keyloc = (KOFF) + kb + it;                                    \
            _Pragma("unroll")                                                 \
            for (int j = (J0); j < 8; ++j) {                                  \
                float sc = fmaf(qx[j], k0, fmaf(qy[j], k1, qz[j] * k2));      \
                float pr = __builtin_amdgcn_exp2f(sc);                        \
                if (MASKED) pr = (keyloc <= ((j << 6) + lane)) ? pr : 0.f;    \
                ac[j][0] = fmaf(pr, v0, ac[j][0]);                            \
                ac[j][1] = fmaf(pr, v1, ac[j][1]);                            \
                ac[j][2] = fmaf(pr, v2, ac[j][2]);                            \
                ac[j][3] += pr;                                               \
            }                                                                 \
        }

    if (dpar < 0)      { KLOOP(0, false, 0)   }   // fully unmasked tile
    else if (dpar == 0){ KLOOP(0, true,  0)   }   // even diagonal
    else               { KLOOP(4, true,  256) }   // odd diagonal (j<4 fully masked)

    #undef KLOOP

    // per-wave partials (16B lane stride: 2-way, free)
    #pragma unroll
    for (int j = 0; j < 8; ++j)
        spart[(wv << 9) + (j << 6) + lane] =
            make_float4(ac[j][0], ac[j][1], ac[j][2], ac[j][3]);
    __syncthreads();

    // block reduce across 4 waves; coalesced transposed pbuf store (512 slots)
    #pragma unroll
    for (int o = 0; o < 512; o += 256) {
        int slot = o + tid;
        float4 a0 = spart[slot];
        float4 a1 = spart[512 + slot];
        float4 a2 = spart[1024 + slot];
        float4 a3 = spart[1536 + slot];
        float4 acc = make_float4(a0.x+a1.x+a2.x+a3.x, a0.y+a1.y+a2.y+a3.y,
                                 a0.z+a1.z+a2.z+a3.z, a0.w+a1.w+a2.w+a3.w);
        p.pbuf[((size_t)bh * 8 + c) * TT + ((size_t)s << 9) + slot] = acc;
    }
}

// ---------------------------------------------------------------------------
// Kernel 3: per-token epilogue (identical to the proven version).
// ---------------------------------------------------------------------------
__global__ __launch_bounds__(256) void epi_kernel(P p) {
    int gid = blockIdx.x * 256 + threadIdx.x;
    if (gid >= NTOK) return;
    int t = gid & (TT - 1);
    int b = gid >> 11;
    int s = t >> 8;

    float x[DM];
    int tok = p.idx[gid];
    #pragma unroll
    for (int j = 0; j < TOKD; ++j) x[j]        = p.tok_emb[tok * TOKD + j];
    #pragma unroll
    for (int j = 0; j < POSD; ++j) x[TOKD + j] = p.pos_enc[t * POSD + j];

    float att[AD];
    #pragma unroll
    for (int hh = 0; hh < NH; ++hh) {
        const float4* pp = p.pbuf + ((size_t)(b * NH + hh) * 8) * TT + t;
        float4 acc = pp[0];
        for (int c = 1; c <= s; ++c) {
            float4 e = pp[(size_t)c * TT];
            acc.x += e.x; acc.y += e.y; acc.z += e.z; acc.w += e.w;
        }
        float inv = 1.f / acc.w;
        att[hh*3+0] = acc.x * inv;
        att[hh*3+1] = acc.y * inv;
        att[hh*3+2] = acc.z * inv;
    }

    float xo[DM];
    #pragma unroll
    for (int j = 0; j < DM; ++j) {
        float sacc = x[j];
        #pragma unroll
        for (int a = 0; a < AD; ++a) sacc = fmaf(p.Wo[j * AD + a], att[a], sacc);
        xo[j] = sacc;
    }

    float m = 0.f;
    #pragma unroll
    for (int j = 0; j < DM; ++j) m += xo[j];
    m *= (1.f / DM);
    float v = 0.f;
    #pragma unroll
    for (int j = 0; j < DM; ++j) { float d = xo[j] - m; v += d * d; }
    v *= (1.f / DM);
    float rs = rsqrtf(v + 1e-5f);
    float h2[DM];
    #pragma unroll
    for (int j = 0; j < DM; ++j)
        h2[j] = (xo[j] - m) * rs * p.ln2w[j] + p.ln2b[j];

    float g[FFND];
    #pragma unroll
    for (int cc = 0; cc < FFND; ++cc) {
        float f = p.b1[cc];
        #pragma unroll
        for (int j = 0; j < DM; ++j) f = fmaf(p.W1[cc * DM + j], h2[j], f);
        g[cc] = 0.5f * f * (1.f + erff(f * 0.70710678118654752f));
    }
    float x2[DM];
    #pragma unroll
    for (int j = 0; j < DM; ++j) {
        float sacc = xo[j] + p.b2[j];
        #pragma unroll
        for (int cc = 0; cc < FFND; ++cc) sacc = fmaf(p.W2[j * FFND + cc], g[cc], sacc);
        x2[j] = sacc;
    }

    m = 0.f;
    #pragma unroll
    for (int j = 0; j < DM; ++j) m += x2[j];
    m *= (1.f / DM);
    v = 0.f;
    #pragma unroll
    for (int j = 0; j < DM; ++j) { float d = x2[j] - m; v += d * d; }
    v *= (1.f / DM);
    rs = rsqrtf(v + 1e-5f);
    float y[DM];
    #pragma unroll
    for (int j = 0; j < DM; ++j)
        y[j] = (x2[j] - m) * rs * p.lnfw[j] + p.lnfb[j];

    float t8[TOKD];
    #pragma unroll
    for (int pp = 0; pp < TOKD; ++pp) {
        float sacc = 0.f;
        #pragma unroll
        for (int j = 0; j < DM; ++j) sacc = fmaf(p.Wh[pp * DM + j], y[j], sacc);
        t8[pp] = sacc;
    }
    float* op = p.out + (size_t)gid * VOCAB;
    #pragma unroll
    for (int vcb = 0; vcb < VOCAB; ++vcb) {
        float sacc = 0.f;
        #pragma unroll
        for (int pp = 0; pp < TOKD; ++pp)
            sacc = fmaf(t8[pp], p.tok_emb[vcb * TOKD + pp], sacc);
        op[vcb] = sacc;
    }
}

// ---------------------------------------------------------------------------
extern "C" void kernel_launch(void* const* d_in, const int* in_sizes, int n_in,
                              void* d_out, int out_size, void* d_ws, size_t ws_size,
                              hipStream_t stream) {
    P p;
    p.idx     = (const int*)d_in[0];
    p.tok_emb = (const float*)d_in[1];
    p.pos_enc = (const float*)d_in[2];
    p.Wq      = (const float*)d_in[3];
    p.Wk      = (const float*)d_in[4];
    p.Wv      = (const float*)d_in[5];
    p.Wo      = (const float*)d_in[6];
    p.ln1w    = (const float*)d_in[7];
    p.ln1b    = (const float*)d_in[8];
    p.ln2w    = (const float*)d_in[9];
    p.ln2b    = (const float*)d_in[10];
    p.lnfw    = (const float*)d_in[11];
    p.lnfb    = (const float*)d_in[12];
    p.W1      = (const float*)d_in[13];
    p.b1      = (const float*)d_in[14];
    p.W2      = (const float*)d_in[15];
    p.b2      = (const float*)d_in[16];
    p.Wh      = (const float*)d_in[17];
    p.out     = (float*)d_out;
    p.qbuf    = (float4*)d_ws;                                  // 1 MB
    p.kvf     = (float4*)((char*)d_ws + (1u << 20));            // 2 MB
    p.pbuf    = (float4*)((char*)d_ws + (3u << 20));            // 8 MB

    prep_kernel<<<NTOK / 256, 256, 0, stream>>>(p);
    attn_kernel<<<NTILE2, 256, 0, stream>>>(p);
    epi_kernel<<<NTOK / 256, 256, 0, stream>>>(p);
}

// Round 6
// 127.076 us; speedup vs baseline: 1.0408x; 1.0408x over previous
//
#include <hip/hip_runtime.h>
#include <math.h>

// Problem constants
#define BB    16
#define TT    2048
#define VOCAB 14
#define TOKD  8
#define POSD  8
#define DM    16      // TOKD + POSD
#define NH    2
#define HD    3
#define AD    6       // NH*HD
#define FFND  3

#define NTOK  (BB*TT)            // 32768
#define BH    (BB*NH)            // 32
#define TPB   36                 // tiles per bh: sum_{s=0..7}(s+1)
#define NTILE (BH*TPB)           // 1152 equal-cost tiles

struct P {
    const int*   idx;
    const float* tok_emb;
    const float* pos_enc;
    const float* Wq;
    const float* Wk;
    const float* Wv;
    const float* Wo;
    const float* ln1w;
    const float* ln1b;
    const float* ln2w;
    const float* ln2b;
    const float* lnfw;
    const float* lnfb;
    const float* W1;
    const float* b1;
    const float* W2;
    const float* b2;
    const float* Wh;
    float*       out;
    float4*      pbuf;   // [BH][8][TT] chunk partials {a0,a1,a2,l}, transposed
};

// LN1 output for token (b, t): embeddings gather + layernorm. ~70 VALU.
__device__ __forceinline__ void ln1_of(const P& p, int b, int t, float* h) {
    float x[DM];
    int tok = p.idx[b * TT + t];
    #pragma unroll
    for (int j = 0; j < TOKD; ++j) x[j]        = p.tok_emb[tok * TOKD + j];
    #pragma unroll
    for (int j = 0; j < POSD; ++j) x[TOKD + j] = p.pos_enc[t * POSD + j];

    float m = 0.f;
    #pragma unroll
    for (int j = 0; j < DM; ++j) m += x[j];
    m *= (1.f / DM);
    float v = 0.f;
    #pragma unroll
    for (int j = 0; j < DM; ++j) { float d = x[j] - m; v += d * d; }
    v *= (1.f / DM);
    float rs = rsqrtf(v + 1e-5f);
    #pragma unroll
    for (int j = 0; j < DM; ++j)
        h[j] = (x[j] - m) * rs * p.ln1w[j] + p.ln1b[j];
}

#define LOADKV(it)                                                             \
    float4 Kr = skv[((kw + (it)) << 1)];                                       \
    float4 Vr = skv[((kw + (it)) << 1) + 1];                                   \
    float k0 = Kr.x, k1 = Kr.y, k2 = Kr.z;                                     \
    float v0 = Vr.x, v1 = Vr.y, v2 = Vr.z;

// ---------------------------------------------------------------------------
// Kernel 1: attention tiles with INLINE PREP. Tile = (bh, 256-query
// super-row s, 256-key chunk c), c <= s. Prologue: thread i preps key-token
// 256c+i (K,V for this block's head only) and query-token 256s+i (prescaled
// Q) straight into LDS — no prep kernel, no qbuf/kvf global round-trip.
// Inner loop / reduce / pbuf store identical to the proven 128.4us version:
// wave wv covers keys [c*256+64wv,+64); lane owns queries 64j+lane, j=0..3;
// one broadcast ds_read_b128 pair per key serves 256 query*key pairs.
// Diagonal tiles: j<wv skipped, j==wv triangular, j>wv unmasked.
// ---------------------------------------------------------------------------
__global__ __launch_bounds__(256) void attn_kernel(P p) {
    __shared__ float4 skv[512];      // 8 KB  f32 K/V records (interleaved)
    __shared__ float4 sq[256];       // 4 KB  prescaled q
    __shared__ float4 spart[1024];   // 16 KB

    const int tid  = threadIdx.x;
    int tile = blockIdx.x;
    int bh   = tile / TPB;
    int r    = tile - bh * TPB;
    int s    = 0;
    while (((s + 1) * (s + 2)) / 2 <= r) ++s;
    int c    = r - (s * (s + 1)) / 2;
    int b    = bh >> 1;              // NH = 2
    int hh   = bh & 1;

    // --- inline prep: key-token for K/V, query-token for Q (this head only)
    {
        float hK[DM];
        ln1_of(p, b, (c << 8) + tid, hK);
        float k0=0.f,k1=0.f,k2=0.f,v0=0.f,v1=0.f,v2=0.f;
        const float* wk = p.Wk + (hh * 3) * 8;
        const float* wv_ = p.Wv + (hh * 3) * 8;
        #pragma unroll
        for (int j = 0; j < 8; ++j) {
            k0 = fmaf(wk[j],      hK[TOKD + j], k0);
            k1 = fmaf(wk[8 + j],  hK[TOKD + j], k1);
            k2 = fmaf(wk[16 + j], hK[TOKD + j], k2);
            v0 = fmaf(wv_[j],      hK[j], v0);
            v1 = fmaf(wv_[8 + j],  hK[j], v1);
            v2 = fmaf(wv_[16 + j], hK[j], v2);
        }
        skv[(tid << 1)]     = make_float4(k0, k1, k2, 0.f);
        skv[(tid << 1) + 1] = make_float4(v0, v1, v2, 0.f);

        float hQ[DM];
        if (c != s) {
            ln1_of(p, b, (s << 8) + tid, hQ);
        } else {
            #pragma unroll
            for (int j = 0; j < DM; ++j) hQ[j] = hK[j];   // same tokens
        }
        const float QS = 1.4426950408889634f / 1.7320508075688772f; // log2e/sqrt(HD)
        float q0=0.f,q1=0.f,q2=0.f;
        const float* wq = p.Wq + (hh * 3) * 8;
        #pragma unroll
        for (int j = 0; j < 8; ++j) {
            q0 = fmaf(wq[j],      hQ[TOKD + j], q0);
            q1 = fmaf(wq[8 + j],  hQ[TOKD + j], q1);
            q2 = fmaf(wq[16 + j], hQ[TOKD + j], q2);
        }
        sq[tid] = make_float4(q0 * QS, q1 * QS, q2 * QS, 0.f);
    }
    __syncthreads();

    int wv   = tid >> 6;
    int lane = tid & 63;
    int kw   = wv << 6;

    float4 qr[4];
    #pragma unroll
    for (int j = 0; j < 4; ++j) qr[j] = sq[(j << 6) + lane];

    float ac[4][4];
    #pragma unroll
    for (int j = 0; j < 4; ++j)
        ac[j][0] = ac[j][1] = ac[j][2] = ac[j][3] = 0.f;

    if (c < s) {
        // fully unmasked: one K/V read serves all 4 query groups
        #pragma unroll 4
        for (int it = 0; it < 64; ++it) {
            LOADKV(it)
            #pragma unroll
            for (int j = 0; j < 4; ++j) {
                float sc = fmaf(qr[j].x, k0, fmaf(qr[j].y, k1, qr[j].z * k2));
                float pr = __builtin_amdgcn_exp2f(sc);
                ac[j][0] = fmaf(pr, v0, ac[j][0]);
                ac[j][1] = fmaf(pr, v1, ac[j][1]);
                ac[j][2] = fmaf(pr, v2, ac[j][2]);
                ac[j][3] += pr;
            }
        }
    } else {
        // diagonal tile: wave wv sees keys 64wv..64wv+63.
        // group j<wv fully masked (skip); j==wv triangular; j>wv unmasked.
        #pragma unroll
        for (int j = 0; j < 4; ++j) {
            if (j < wv) continue;              // wave-uniform skip
            if (j == wv) {
                #pragma unroll 4
                for (int it = 0; it < 64; ++it) {
                    LOADKV(it)
                    float sc = fmaf(qr[j].x, k0, fmaf(qr[j].y, k1, qr[j].z * k2));
                    float pr = __builtin_amdgcn_exp2f(sc);
                    pr = (it <= lane) ? pr : 0.f;
                    ac[j][0] = fmaf(pr, v0, ac[j][0]);
                    ac[j][1] = fmaf(pr, v1, ac[j][1]);
                    ac[j][2] = fmaf(pr, v2, ac[j][2]);
                    ac[j][3] += pr;
                }
            } else {
                #pragma unroll 4
                for (int it = 0; it < 64; ++it) {
                    LOADKV(it)
                    float sc = fmaf(qr[j].x, k0, fmaf(qr[j].y, k1, qr[j].z * k2));
                    float pr = __builtin_amdgcn_exp2f(sc);
                    ac[j][0] = fmaf(pr, v0, ac[j][0]);
                    ac[j][1] = fmaf(pr, v1, ac[j][1]);
                    ac[j][2] = fmaf(pr, v2, ac[j][2]);
                    ac[j][3] += pr;
                }
            }
        }
    }

    // per-wave partials (16B lane stride: 2-way, free)
    #pragma unroll
    for (int j = 0; j < 4; ++j)
        spart[(wv << 8) + (j << 6) + lane] =
            make_float4(ac[j][0], ac[j][1], ac[j][2], ac[j][3]);
    __syncthreads();

    // block reduce across 4 waves; coalesced transposed pbuf store
    float4 p0 = spart[tid];
    float4 p1 = spart[256 + tid];
    float4 p2 = spart[512 + tid];
    float4 p3 = spart[768 + tid];
    float4 acc = make_float4(p0.x+p1.x+p2.x+p3.x, p0.y+p1.y+p2.y+p3.y,
                             p0.z+p1.z+p2.z+p3.z, p0.w+p1.w+p2.w+p3.w);
    p.pbuf[((size_t)bh * 8 + c) * TT + (s << 8) + tid] = acc;
}

// ---------------------------------------------------------------------------
// Kernel 2: per-token epilogue (identical to the proven version).
// ---------------------------------------------------------------------------
__global__ __launch_bounds__(256) void epi_kernel(P p) {
    int gid = blockIdx.x * 256 + threadIdx.x;
    if (gid >= NTOK) return;
    int t = gid & (TT - 1);
    int b = gid >> 11;
    int s = t >> 8;

    float x[DM];
    int tok = p.idx[gid];
    #pragma unroll
    for (int j = 0; j < TOKD; ++j) x[j]        = p.tok_emb[tok * TOKD + j];
    #pragma unroll
    for (int j = 0; j < POSD; ++j) x[TOKD + j] = p.pos_enc[t * POSD + j];

    float att[AD];
    #pragma unroll
    for (int hh = 0; hh < NH; ++hh) {
        const float4* pp = p.pbuf + ((size_t)(b * NH + hh) * 8) * TT + t;
        float4 acc = pp[0];
        for (int c = 1; c <= s; ++c) {
            float4 e = pp[(size_t)c * TT];
            acc.x += e.x; acc.y += e.y; acc.z += e.z; acc.w += e.w;
        }
        float inv = 1.f / acc.w;
        att[hh*3+0] = acc.x * inv;
        att[hh*3+1] = acc.y * inv;
        att[hh*3+2] = acc.z * inv;
    }

    float xo[DM];
    #pragma unroll
    for (int j = 0; j < DM; ++j) {
        float sacc = x[j];
        #pragma unroll
        for (int a = 0; a < AD; ++a) sacc = fmaf(p.Wo[j * AD + a], att[a], sacc);
        xo[j] = sacc;
    }

    float m = 0.f;
    #pragma unroll
    for (int j = 0; j < DM; ++j) m += xo[j];
    m *= (1.f / DM);
    float v = 0.f;
    #pragma unroll
    for (int j = 0; j < DM; ++j) { float d = xo[j] - m; v += d * d; }
    v *= (1.f / DM);
    float rs = rsqrtf(v + 1e-5f);
    float h2[DM];
    #pragma unroll
    for (int j = 0; j < DM; ++j)
        h2[j] = (xo[j] - m) * rs * p.ln2w[j] + p.ln2b[j];

    float g[FFND];
    #pragma unroll
    for (int cc = 0; cc < FFND; ++cc) {
        float f = p.b1[cc];
        #pragma unroll
        for (int j = 0; j < DM; ++j) f = fmaf(p.W1[cc * DM + j], h2[j], f);
        g[cc] = 0.5f * f * (1.f + erff(f * 0.70710678118654752f));
    }
    float x2[DM];
    #pragma unroll
    for (int j = 0; j < DM; ++j) {
        float sacc = xo[j] + p.b2[j];
        #pragma unroll
        for (int cc = 0; cc < FFND; ++cc) sacc = fmaf(p.W2[j * FFND + cc], g[cc], sacc);
        x2[j] = sacc;
    }

    m = 0.f;
    #pragma unroll
    for (int j = 0; j < DM; ++j) m += x2[j];
    m *= (1.f / DM);
    v = 0.f;
    #pragma unroll
    for (int j = 0; j < DM; ++j) { float d = x2[j] - m; v += d * d; }
    v *= (1.f / DM);
    rs = rsqrtf(v + 1e-5f);
    float y[DM];
    #pragma unroll
    for (int j = 0; j < DM; ++j)
        y[j] = (x2[j] - m) * rs * p.lnfw[j] + p.lnfb[j];

    float t8[TOKD];
    #pragma unroll
    for (int pp = 0; pp < TOKD; ++pp) {
        float sacc = 0.f;
        #pragma unroll
        for (int j = 0; j < DM; ++j) sacc = fmaf(p.Wh[pp * DM + j], y[j], sacc);
        t8[pp] = sacc;
    }
    float* op = p.out + (size_t)gid * VOCAB;
    #pragma unroll
    for (int vcb = 0; vcb < VOCAB; ++vcb) {
        float sacc = 0.f;
        #pragma unroll
        for (int pp = 0; pp < TOKD; ++pp)
            sacc = fmaf(t8[pp], p.tok_emb[vcb * TOKD + pp], sacc);
        op[vcb] = sacc;
    }
}

// ---------------------------------------------------------------------------
extern "C" void kernel_launch(void* const* d_in, const int* in_sizes, int n_in,
                              void* d_out, int out_size, void* d_ws, size_t ws_size,
                              hipStream_t stream) {
    P p;
    p.idx     = (const int*)d_in[0];
    p.tok_emb = (const float*)d_in[1];
    p.pos_enc = (const float*)d_in[2];
    p.Wq      = (const float*)d_in[3];
    p.Wk      = (const float*)d_in[4];
    p.Wv      = (const float*)d_in[5];
    p.Wo      = (const float*)d_in[6];
    p.ln1w    = (const float*)d_in[7];
    p.ln1b    = (const float*)d_in[8];
    p.ln2w    = (const float*)d_in[9];
    p.ln2b    = (const float*)d_in[10];
    p.lnfw    = (const float*)d_in[11];
    p.lnfb    = (const float*)d_in[12];
    p.W1      = (const float*)d_in[13];
    p.b1      = (const float*)d_in[14];
    p.W2      = (const float*)d_in[15];
    p.b2      = (const float*)d_in[16];
    p.Wh      = (const float*)d_in[17];
    p.out     = (float*)d_out;
    p.pbuf    = (float4*)d_ws;                                  // 8 MB

    attn_kernel<<<NTILE, 256, 0, stream>>>(p);
    epi_kernel<<<NTOK / 256, 256, 0, stream>>>(p);
}